// Round 11
// baseline (248.937 us; speedup 1.0000x reference)
//
#include <hip/hip_runtime.h>

// Problem constants
#define BN   4
#define NN   128
#define INF  256
#define EF   128
#define OUTF 128
#define EPSF 1e-5f
#define NEGF -998244352.0f   // bf16(1e9); matches the bf16-rounded np reference

typedef __attribute__((ext_vector_type(8))) short short8;
typedef __attribute__((ext_vector_type(4))) float f32x4;

#define MFMA16(a, b, c) __builtin_amdgcn_mfma_f32_16x16x32_bf16(a, b, c, 0, 0, 0)

__device__ __forceinline__ unsigned short f2bf(float f) {
    unsigned u = __float_as_uint(f);
    u += 0x7fffu + ((u >> 16) & 1u);
    return (unsigned short)(u >> 16);
}
__device__ __forceinline__ unsigned pack2(float a, float b) {
    return (unsigned)f2bf(a) | ((unsigned)f2bf(b) << 16);
}

// ---- workspace layout (float offsets) ----
constexpr size_t TRI1 = 0;            // B*N*8   tri_1 (masked)
constexpr size_t TRI2 = 4096;
constexpr size_t TRI3 = 8192;
constexpr size_t MSG1 = 12288;        // B*N*128 msg_1 (masked)
constexpr size_t MSG2 = 77824;
constexpr size_t ZWU1 = 143360;
constexpr size_t TRIG = 208896;       // B*8
constexpr size_t MSGG = 209920;       // B*128
constexpr size_t E1T  = 210944;       // B*N*N*8  fp32 [b][j][i][c]
constexpr size_t E2T  = 735232;       // B*N*N*8  fp32 [b][k][i][c]
constexpr size_t E3N  = 1259520;      // B*N*N*8  fp32 [b][j][k][c]
constexpr size_t PREPF = 1783808;     // bf16 prepped weights (ushort region)

// prep (ushort units), MFMA-fragment order:
// ((ks*8 + t)*64 + lane)*8 + jj == W^T[16t + (lane&15)][ks*32 + (lane>>4)*8 + jj]
constexpr int W1T_OFF  = 0;
constexpr int W2T_OFF  = 16384;
constexpr int WMET_OFF = 32768;

// ---- output layout (float offsets): ret, msgs, tri_msgs ----
constexpr size_t O_RET = 0;
constexpr size_t O_MSG = 65536;
constexpr size_t O_TRI = 131072;

__device__ __forceinline__ int detect_int(const void* mask) {
    const unsigned char* m = (const unsigned char*)mask;
    return (m[1] | m[2] | m[3]) == 0 ? 1 : 0;
}
__device__ __forceinline__ bool rdbool(const void* p, size_t idx, int isInt) {
    if (isInt) return ((const int*)p)[idx] != 0;
    return ((const unsigned char*)p)[idx] != 0;
}

// ============================================================
// K1: tri-e half-blocks (0..1023: 64 j-rows each, 17.4KB LDS) +
//     z proj (1024..1535) + graph (1536..1539) + weight prep (1540..1731).
// Small LDS + (256,8) -> up to 8 blocks/CU.
// ============================================================
__global__ __launch_bounds__(256, 8) void k_pre(
    const float* __restrict__ z, const float* __restrict__ e, const void* __restrict__ mask,
    const float* __restrict__ Wt1, const float* __restrict__ Wt2, const float* __restrict__ Wt3,
    const float* __restrict__ Wm1, const float* __restrict__ Wm2, const float* __restrict__ WU1,
    const float* __restrict__ g, const float* __restrict__ Wg, const float* __restrict__ Wmg,
    const float* __restrict__ W1, const float* __restrict__ W2, const float* __restrict__ Wme,
    const float* __restrict__ We1, const float* __restrict__ We2, const float* __restrict__ We3,
    float* __restrict__ ws, unsigned short* __restrict__ prep)
{
    int bx = blockIdx.x, tid = threadIdx.x;
    __shared__ __align__(16) unsigned char smem[64 * 136 * 2];   // 17408 B

    if (bx < 1024) {
        // ---------- tri-e projection: half-block = (b, i, 64-row half) ----------
        unsigned short* Ab = (unsigned short*)smem;
        int bi = bx >> 1, h = bx & 1;
        int b = bi >> 7, i = bi & 127;
        int R0 = 64 * h;
        int lane = tid & 63, w = tid >> 6, q = lane >> 4, n = lane & 15;
        // coalesced staging: wave w stages rows 16w..16w+15 (2 rows/instr)
        {
            int halfl = lane >> 5, c4 = (lane & 31) * 4;
            #pragma unroll
            for (int it = 0; it < 8; it++) {
                int lr = 16 * w + 2 * it + halfl;
                float4 v = *(const float4*)(e + (size_t)bi * 16384 + (size_t)(R0 + lr) * 128 + c4);
                unsigned* dst = (unsigned*)&Ab[lr * 136 + c4];
                dst[0] = pack2(v.x, v.y);
                dst[1] = pack2(v.z, v.w);
            }
        }
        // gather packed-We B fragments (cols: We1|We2|We3|0), L1-hot 4KB arrays
        short8 bfrag[4][2];
        #pragma unroll
        for (int t = 0; t < 2; t++) {
            int col = 16 * t + n;
            const float* Wsel = (col < 8) ? We1 : (col < 16 ? We2 : We3);
            int csel = col & 7;
            float mval = (col < 24) ? 1.f : 0.f;
            #pragma unroll
            for (int ks = 0; ks < 4; ks++) {
                union { short8 s; unsigned short u[8]; } tmp;
                #pragma unroll
                for (int jj = 0; jj < 8; jj++) {
                    int k = ks * 32 + q * 8 + jj;
                    tmp.u[jj] = f2bf(Wsel[k * 8 + csel] * mval);
                }
                bfrag[ks][t] = tmp.s;
            }
        }
        __builtin_amdgcn_wave_barrier();

        f32x4 ac2[2];
        ac2[0] = 0.f; ac2[1] = 0.f;
        #pragma unroll
        for (int ks = 0; ks < 4; ks++) {
            int k0 = ks * 32 + q * 8;
            short8 a0 = *(const short8*)&Ab[(16 * w + n) * 136 + k0];
            #pragma unroll
            for (int t = 0; t < 2; t++)
                ac2[t] = MFMA16(a0, bfrag[ks][t], ac2[t]);
        }
        #pragma unroll
        for (int reg = 0; reg < 4; reg++) {
            int row = R0 + 16 * w + 4 * q + reg;
            float v0 = ac2[0][reg];
            if (n < 8) ws[E1T + ((size_t)(b * 128 + row) * 128 + i) * 8 + n] = v0;
            else       ws[E2T + ((size_t)(b * 128 + row) * 128 + i) * 8 + (n - 8)] = v0;
            if (n < 8) ws[E3N + ((size_t)bi * 128 + row) * 8 + n] = ac2[1][reg];
        }
        return;
    }
    if (bx < 1536) {
        // ---------- z-row projections (2-way split accumulators for ILP) ----------
        int bn = bx - 1024;
        int isInt = detect_int(mask);
        float* zr = (float*)smem;
        zr[tid] = z[(size_t)bn * INF + tid];
        __syncthreads();
        float mk = rdbool(mask, bn, isInt) ? 1.f : 0.f;
        for (int idx = tid; idx < 408; idx += 256) {
            const float* W; int c; size_t dst; int width; bool msk;
            if (idx < 8)        { W = Wt1; c = idx;       dst = TRI1 + (size_t)bn * 8;   width = 8;   msk = true;  }
            else if (idx < 16)  { W = Wt2; c = idx - 8;   dst = TRI2 + (size_t)bn * 8;   width = 8;   msk = true;  }
            else if (idx < 24)  { W = Wt3; c = idx - 16;  dst = TRI3 + (size_t)bn * 8;   width = 8;   msk = true;  }
            else if (idx < 152) { W = Wm1; c = idx - 24;  dst = MSG1 + (size_t)bn * 128; width = 128; msk = true;  }
            else if (idx < 280) { W = Wm2; c = idx - 152; dst = MSG2 + (size_t)bn * 128; width = 128; msk = true;  }
            else                { W = WU1; c = idx - 280; dst = ZWU1 + (size_t)bn * 128; width = 128; msk = false; }
            float a0 = 0.f, a1 = 0.f;
            #pragma unroll 8
            for (int k = 0; k < INF; k += 2) {
                a0 += zr[k] * W[k * width + c];
                a1 += zr[k + 1] * W[(k + 1) * width + c];
            }
            float acc = a0 + a1;
            ws[dst + c] = msk ? acc * mk : acc;
        }
        return;
    }
    if (bx < 1540) {
        // ---------- graph_fts projections ----------
        int b = bx - 1536;
        float* gr = (float*)smem;
        if (tid < 128) gr[tid] = g[b * 128 + tid];
        __syncthreads();
        if (tid < 8) {
            float a = 0.f;
            for (int k = 0; k < 128; k++) a += gr[k] * Wg[k * 8 + tid];
            ws[TRIG + b * 8 + tid] = a;
        } else if (tid >= 128) {
            int c = tid - 128;
            float a = 0.f;
            for (int k = 0; k < 128; k++) a += gr[k] * Wmg[k * 128 + c];
            ws[MSGG + b * 128 + c] = a;
        }
        return;
    }
    // ---------- weight prep (fragment-order), W1/W2/Wme only ----------
    {
        int idx = (bx - 1540) * 256 + tid;   // < 49152
        const float* W = (idx < 16384) ? W1 : (idx < 32768 ? W2 : Wme);
        int local = idx & 16383;
        int f = local >> 3, jj = local & 7;
        int lane = f & 63, fg = f >> 6;
        int t = fg & 7, ks = fg >> 3;
        int n = lane & 15, q = lane >> 4;
        int row = 16 * t + n;
        int k = ks * 32 + q * 8 + jj;
        prep[idx] = f2bf(W[k * 128 + row]);
    }
}

// ============================================================
// K2: pair-MLP blocks (bx%3<2) + triplet-pool blocks (bx%3==2).
// grid 768, block 256, LDS 36.9KB -> 4 blocks/CU.
// Triplet inner loop on ext-vector float4 (packed VALU adds).
// ============================================================
constexpr int PQSTR = 268;   // floats; 268 % 32 = 12

__global__ __launch_bounds__(256, 4) void k_main(
    const float* __restrict__ e, const void* __restrict__ mask, const void* __restrict__ adj,
    const float* __restrict__ ln1s, const float* __restrict__ ln1o,
    const float* __restrict__ ln2s, const float* __restrict__ ln2o,
    const unsigned short* __restrict__ prep, const float* __restrict__ WU3,
    float* __restrict__ ws, float* __restrict__ out)
{
    int bx = blockIdx.x, tid = threadIdx.x;
    int gct = bx / 3, r3 = bx - gct * 3;
    __shared__ __align__(16) unsigned char smem[128 * 136 * 2 + 2048];
    int lane = tid & 63, w = tid >> 6, q = lane >> 4, n = lane & 15;

    if (r3 == 2) {
        // ================= triplet max-plus pooling: 16x16 (j,k) tile =================
        int g = gct;
        int j0 = ((g >> 3) & 7) * 16, k0 = (g & 7) * 16, b = g >> 6;
        int isInt = detect_int(mask);
        float* Pl = (float*)smem;                        // [16][268]
        float* Ql = (float*)(smem + 16 * PQSTR * 4);     // [16][268]
        float* pooled = (float*)smem;                    // alias: [8][260] c-major
        __shared__ unsigned char mloc[128];
        if (tid < 128) mloc[tid] = rdbool(mask, b * 128 + tid, isInt) ? 1 : 0;

        // WU3 fragment in registers (coalesced global loads; L2-hot)
        int col4 = (tid & 31) * 4, rowgrp = tid >> 5;
        float4 wvr[8];
        #pragma unroll
        for (int c = 0; c < 8; c++) wvr[c] = *(const float4*)(WU3 + c * 128 + col4);

        int tj = tid >> 4, tk = tid & 15;
        f32x4 accM[2], accU[2];
        accM[0] = NEGF; accM[1] = NEGF; accU[0] = NEGF; accU[1] = NEGF;

        for (int i0 = 0; i0 < 128; i0 += 32) {
            __syncthreads();   // previous chunk consumed
            {
                float4 t1c = *(const float4*)(ws + TRI1 + (size_t)b * 1024 + i0 * 8 + lane * 4);
                #pragma unroll
                for (int r4 = 0; r4 < 4; r4++) {
                    int row = 4 * w + r4;
                    float4 ev = *(const float4*)(ws + E1T + (size_t)(b * 128 + j0 + row) * 1024 + i0 * 8 + lane * 4);
                    float4 qv = *(const float4*)(ws + E2T + (size_t)(b * 128 + k0 + row) * 1024 + i0 * 8 + lane * 4);
                    float4 pv;
                    pv.x = ev.x + t1c.x; pv.y = ev.y + t1c.y;
                    pv.z = ev.z + t1c.z; pv.w = ev.w + t1c.w;
                    *(float4*)(Pl + row * PQSTR + lane * 4) = pv;   // contiguous 1KB wave write
                    *(float4*)(Ql + row * PQSTR + lane * 4) = qv;
                }
            }
            __syncthreads();   // staged
            const float* pp = Pl + tj * PQSTR;
            const float* qq = Ql + tk * PQSTR;
            for (int ii = 0; ii < 32; ii++) {
                bool m_i = mloc[i0 + ii] != 0;   // wave-uniform
                f32x4 p0 = *(const f32x4*)(pp + ii * 8);
                f32x4 p1 = *(const f32x4*)(pp + ii * 8 + 4);
                f32x4 q0 = *(const f32x4*)(qq + ii * 8);
                f32x4 q1 = *(const f32x4*)(qq + ii * 8 + 4);
                f32x4 v0 = p0 + q0;   // packed fp32 adds
                f32x4 v1 = p1 + q1;
                if (m_i) {
                    accM[0] = __builtin_elementwise_max(accM[0], v0);
                    accM[1] = __builtin_elementwise_max(accM[1], v1);
                } else {
                    accU[0] = __builtin_elementwise_max(accU[0], v0);
                    accU[1] = __builtin_elementwise_max(accU[1], v1);
                }
            }
        }
        f32x4 sel[2];
        {
            bool all_i = (mloc[j0 + tj] | mloc[k0 + tk]) != 0;
            if (all_i) {
                sel[0] = __builtin_elementwise_max(accM[0], accU[0]);
                sel[1] = __builtin_elementwise_max(accM[1], accU[1]);
            } else {
                sel[0] = accM[0]; sel[1] = accM[1];
            }
        }
        __syncthreads();   // P/Q reads done; safe to alias pooled
        {
            const float* t2 = ws + TRI2 + (size_t)(b * 128 + j0 + tj) * 8;
            const float* t3 = ws + TRI3 + (size_t)(b * 128 + k0 + tk) * 8;
            const float* e3 = ws + E3N + ((size_t)(b * 128 + j0 + tj) * 128 + (k0 + tk)) * 8;
            const float* tg = ws + TRIG + (size_t)b * 8;
            #pragma unroll
            for (int c = 0; c < 8; c++)
                pooled[c * 260 + tid] = sel[c >> 2][c & 3] + t2[c] + t3[c] + e3[c] + tg[c];
        }
        __syncthreads();
        // epilogue: relu(pooled @ WU3); pooled reads broadcast, no LDS weights
        #pragma unroll
        for (int pass = 0; pass < 32; pass++) {
            int p = pass * 8 + rowgrp;
            float4 s = { 0.f, 0.f, 0.f, 0.f };
            #pragma unroll
            for (int c = 0; c < 8; c++) {
                float pv = pooled[c * 260 + p];
                s.x += pv * wvr[c].x; s.y += pv * wvr[c].y;
                s.z += pv * wvr[c].z; s.w += pv * wvr[c].w;
            }
            s.x = fmaxf(s.x, 0.f); s.y = fmaxf(s.y, 0.f);
            s.z = fmaxf(s.z, 0.f); s.w = fmaxf(s.w, 0.f);
            int pj = p >> 4, pk = p & 15;
            *(float4*)(out + O_TRI + ((size_t)(b * 128 + j0 + pj) * 128 + (k0 + pk)) * 128 + col4) = s;
        }
        return;
    }

    // ================= pair MLP: block = one (b,j) =================
    unsigned short* Ab = (unsigned short*)smem;
    float* pw = (float*)(smem + 128 * 136 * 2);
    int bj = gct * 2 + r3;
    int b = bj >> 7, j = bj & 127;
    int isInt = detect_int(mask);

    {
        int half = lane >> 5, c4 = (lane & 31) * 4;
        #pragma unroll
        for (int it = 0; it < 16; it++) {
            int row = 32 * w + 2 * it + half;
            float4 v = *(const float4*)(e + (((size_t)b * 128 + row) * 128 + j) * 128 + c4);
            unsigned* dst = (unsigned*)&Ab[row * 136 + c4];
            dst[0] = pack2(v.x, v.y);
            dst[1] = pack2(v.z, v.w);
        }
    }
    __builtin_amdgcn_wave_barrier();

    f32x4 acc[2][8];
    #pragma unroll
    for (int rt = 0; rt < 2; rt++)
        #pragma unroll
        for (int t = 0; t < 8; t++) acc[rt][t] = 0.f;

    #pragma unroll
    for (int ks = 0; ks < 4; ks++) {
        int k0 = ks * 32 + q * 8;
        short8 a0 = *(const short8*)&Ab[(32 * w + n) * 136 + k0];
        short8 a1 = *(const short8*)&Ab[(32 * w + 16 + n) * 136 + k0];
        #pragma unroll
        for (int t = 0; t < 8; t++) {
            short8 bt = *(const short8*)&prep[WMET_OFF + ((ks * 8 + t) * 64 + lane) * 8];
            acc[0][t] = MFMA16(a0, bt, acc[0][t]);
            acc[1][t] = MFMA16(a1, bt, acc[1][t]);
        }
    }

    float msum[8];
    #pragma unroll
    for (int t = 0; t < 8; t++)
        msum[t] = ws[MSG1 + (size_t)bj * 128 + 16 * t + n] + ws[MSGG + (size_t)b * 128 + 16 * t + n];
    float adjm[2][4];
    float rs[2][4], rss[2][4];
    #pragma unroll
    for (int rt = 0; rt < 2; rt++)
        #pragma unroll
        for (int reg = 0; reg < 4; reg++) {
            int row = 32 * w + 16 * rt + 4 * q + reg;
            bool av = rdbool(adj, ((size_t)b * 128 + row) * 128 + j, isInt);
            adjm[rt][reg] = av ? 1.f : 0.f;
            float s = 0.f, ssq = 0.f;
            #pragma unroll
            for (int t = 0; t < 8; t++) {
                float v = acc[rt][t][reg] * adjm[rt][reg]
                        + ws[MSG2 + ((size_t)b * 128 + row) * 128 + 16 * t + n] + msum[t];
                acc[rt][t][reg] = v;
                s += v; ssq += v * v;
            }
            rs[rt][reg] = s; rss[rt][reg] = ssq;
        }
    #pragma unroll
    for (int d = 1; d < 16; d <<= 1) {
        #pragma unroll
        for (int rt = 0; rt < 2; rt++)
            #pragma unroll
            for (int reg = 0; reg < 4; reg++) {
                rs[rt][reg]  += __shfl_xor(rs[rt][reg], d, 64);
                rss[rt][reg] += __shfl_xor(rss[rt][reg], d, 64);
            }
    }
    {
        float s1v[8], o1v[8];
        #pragma unroll
        for (int t = 0; t < 8; t++) { s1v[t] = ln1s[16 * t + n]; o1v[t] = ln1o[16 * t + n]; }
        #pragma unroll
        for (int rt = 0; rt < 2; rt++)
            #pragma unroll
            for (int reg = 0; reg < 4; reg++) {
                float mu = rs[rt][reg] * (1.f / 128);
                float inv = rsqrtf(rss[rt][reg] * (1.f / 128) - mu * mu + EPSF);
                int row = 32 * w + 16 * rt + 4 * q + reg;
                #pragma unroll
                for (int t = 0; t < 8; t++) {
                    float v = fmaxf(s1v[t] * inv * (acc[rt][t][reg] - mu) + o1v[t], 0.f);
                    Ab[row * 136 + 16 * t + n] = f2bf(v);
                }
            }
    }
    __builtin_amdgcn_wave_barrier();

    #pragma unroll
    for (int rt = 0; rt < 2; rt++)
        #pragma unroll
        for (int t = 0; t < 8; t++) acc[rt][t] = 0.f;
    #pragma unroll
    for (int ks = 0; ks < 4; ks++) {
        int k0 = ks * 32 + q * 8;
        short8 a0 = *(const short8*)&Ab[(32 * w + n) * 136 + k0];
        short8 a1 = *(const short8*)&Ab[(32 * w + 16 + n) * 136 + k0];
        #pragma unroll
        for (int t = 0; t < 8; t++) {
            short8 bt = *(const short8*)&prep[W1T_OFF + ((ks * 8 + t) * 64 + lane) * 8];
            acc[0][t] = MFMA16(a0, bt, acc[0][t]);
            acc[1][t] = MFMA16(a1, bt, acc[1][t]);
        }
    }
    #pragma unroll
    for (int rt = 0; rt < 2; rt++)
        #pragma unroll
        for (int reg = 0; reg < 4; reg++) {
            float s = 0.f, ssq = 0.f;
            #pragma unroll
            for (int t = 0; t < 8; t++) { float v = acc[rt][t][reg]; s += v; ssq += v * v; }
            rs[rt][reg] = s; rss[rt][reg] = ssq;
        }
    #pragma unroll
    for (int d = 1; d < 16; d <<= 1) {
        #pragma unroll
        for (int rt = 0; rt < 2; rt++)
            #pragma unroll
            for (int reg = 0; reg < 4; reg++) {
                rs[rt][reg]  += __shfl_xor(rs[rt][reg], d, 64);
                rss[rt][reg] += __shfl_xor(rss[rt][reg], d, 64);
            }
    }
    {
        float s2v[8], o2v[8];
        #pragma unroll
        for (int t = 0; t < 8; t++) { s2v[t] = ln2s[16 * t + n]; o2v[t] = ln2o[16 * t + n]; }
        #pragma unroll
        for (int rt = 0; rt < 2; rt++)
            #pragma unroll
            for (int reg = 0; reg < 4; reg++) {
                float mu = rs[rt][reg] * (1.f / 128);
                float inv = rsqrtf(rss[rt][reg] * (1.f / 128) - mu * mu + EPSF);
                int row = 32 * w + 16 * rt + 4 * q + reg;
                #pragma unroll
                for (int t = 0; t < 8; t++) {
                    float v = fmaxf(s2v[t] * inv * (acc[rt][t][reg] - mu) + o2v[t], 0.f);
                    Ab[row * 136 + 16 * t + n] = f2bf(v);
                }
            }
    }
    __builtin_amdgcn_wave_barrier();

    #pragma unroll
    for (int rt = 0; rt < 2; rt++)
        #pragma unroll
        for (int t = 0; t < 8; t++) acc[rt][t] = 0.f;
    #pragma unroll
    for (int ks = 0; ks < 4; ks++) {
        int k0 = ks * 32 + q * 8;
        short8 a0 = *(const short8*)&Ab[(32 * w + n) * 136 + k0];
        short8 a1 = *(const short8*)&Ab[(32 * w + 16 + n) * 136 + k0];
        #pragma unroll
        for (int t = 0; t < 8; t++) {
            short8 bt = *(const short8*)&prep[W2T_OFF + ((ks * 8 + t) * 64 + lane) * 8];
            acc[0][t] = MFMA16(a0, bt, acc[0][t]);
            acc[1][t] = MFMA16(a1, bt, acc[1][t]);
        }
    }
    float colmax[8];
    #pragma unroll
    for (int t = 0; t < 8; t++) colmax[t] = NEGF;
    #pragma unroll
    for (int rt = 0; rt < 2; rt++)
        #pragma unroll
        for (int reg = 0; reg < 4; reg++) {
            if (adjm[rt][reg] > 0.f) {
                #pragma unroll
                for (int t = 0; t < 8; t++) colmax[t] = fmaxf(colmax[t], acc[rt][t][reg]);
            }
        }
    #pragma unroll
    for (int t = 0; t < 8; t++) {
        colmax[t] = fmaxf(colmax[t], __shfl_xor(colmax[t], 16, 64));
        colmax[t] = fmaxf(colmax[t], __shfl_xor(colmax[t], 32, 64));
    }
    if (lane < 16) {
        #pragma unroll
        for (int t = 0; t < 8; t++) pw[w * 128 + 16 * t + lane] = colmax[t];
    }
    __syncthreads();
    if (tid < 128) {
        float mx = fmaxf(fmaxf(pw[tid], pw[128 + tid]), fmaxf(pw[256 + tid], pw[384 + tid]));
        out[O_MSG + (size_t)bj * 128 + tid] = mx;
    }
}

// ============================================================
// K3: ret = LN(z@WU1 + msgs@WU2).  grid 512, block 128
// ============================================================
__global__ __launch_bounds__(128) void k_final(
    const float* __restrict__ ws, const float* __restrict__ WU2,
    const float* __restrict__ lnfs, const float* __restrict__ lnfo,
    float* __restrict__ out)
{
    int bn = blockIdx.x, tid = threadIdx.x;
    __shared__ float mrow[128];
    __shared__ float red[4];
    mrow[tid] = out[O_MSG + (size_t)bn * 128 + tid];
    __syncthreads();
    float y = ws[ZWU1 + (size_t)bn * 128 + tid];
    #pragma unroll 8
    for (int k = 0; k < 128; k++) y += mrow[k] * WU2[k * 128 + tid];
    float s = y, ss = y * y;
    for (int d = 1; d < 64; d <<= 1) { s += __shfl_xor(s, d, 64); ss += __shfl_xor(ss, d, 64); }
    if ((tid & 63) == 0) { red[(tid >> 6) * 2] = s; red[(tid >> 6) * 2 + 1] = ss; }
    __syncthreads();
    float S = red[0] + red[2], SS = red[1] + red[3];
    float m_ = S * (1.f / 128), v_ = SS * (1.f / 128) - m_ * m_;
    float r = rsqrtf(v_ + EPSF);
    out[O_RET + (size_t)bn * 128 + tid] = lnfs[tid] * r * (y - m_) + lnfo[tid];
}

// ============================================================
extern "C" void kernel_launch(void* const* d_in, const int* in_sizes, int n_in,
                              void* d_out, int out_size, void* d_ws, size_t ws_size,
                              hipStream_t stream)
{
    const float* z    = (const float*)d_in[0];
    const float* e    = (const float*)d_in[1];
    const float* gf   = (const float*)d_in[2];
    const void*  mask = d_in[3];
    const void*  adj  = d_in[4];
    const float* Wt1 = (const float*)d_in[5];
    const float* Wt2 = (const float*)d_in[6];
    const float* Wt3 = (const float*)d_in[7];
    const float* We1 = (const float*)d_in[8];
    const float* We2 = (const float*)d_in[9];
    const float* We3 = (const float*)d_in[10];
    const float* Wg  = (const float*)d_in[11];
    const float* Wm1 = (const float*)d_in[12];
    const float* Wm2 = (const float*)d_in[13];
    const float* Wme = (const float*)d_in[14];
    const float* Wmg = (const float*)d_in[15];
    const float* ln1s = (const float*)d_in[16];
    const float* ln1o = (const float*)d_in[17];
    const float* W1   = (const float*)d_in[18];
    const float* ln2s = (const float*)d_in[19];
    const float* ln2o = (const float*)d_in[20];
    const float* W2   = (const float*)d_in[21];
    const float* WU1  = (const float*)d_in[22];
    const float* WU2  = (const float*)d_in[23];
    const float* WU3  = (const float*)d_in[24];
    const float* lnfs = (const float*)d_in[25];
    const float* lnfo = (const float*)d_in[26];
    float* out = (float*)d_out;
    float* ws  = (float*)d_ws;
    unsigned short* prep = (unsigned short*)(ws + PREPF);

    hipLaunchKernelGGL(k_pre, dim3(1732), dim3(256), 0, stream,
                       z, e, mask, Wt1, Wt2, Wt3, Wm1, Wm2, WU1, gf, Wg, Wmg,
                       W1, W2, Wme, We1, We2, We3, ws, prep);
    hipLaunchKernelGGL(k_main, dim3(768), dim3(256), 0, stream,
                       e, mask, adj, ln1s, ln1o, ln2s, ln2o, prep, WU3, ws, out);
    hipLaunchKernelGGL(k_final, dim3(512), dim3(128), 0, stream,
                       ws, WU2, lnfs, lnfo, out);
}

// Round 12
// 193.787 us; speedup vs baseline: 1.2846x; 1.2846x over previous
//
#include <hip/hip_runtime.h>

// Problem constants
#define BN   4
#define NN   128
#define INF  256
#define EF   128
#define OUTF 128
#define EPSF 1e-5f
#define NEGF -998244352.0f   // bf16(1e9); matches the bf16-rounded np reference

typedef __attribute__((ext_vector_type(8))) short short8;
typedef __attribute__((ext_vector_type(4))) float f32x4;

#define MFMA16(a, b, c) __builtin_amdgcn_mfma_f32_16x16x32_bf16(a, b, c, 0, 0, 0)

__device__ __forceinline__ unsigned short f2bf(float f) {
    unsigned u = __float_as_uint(f);
    u += 0x7fffu + ((u >> 16) & 1u);
    return (unsigned short)(u >> 16);
}
__device__ __forceinline__ unsigned pack2(float a, float b) {
    return (unsigned)f2bf(a) | ((unsigned)f2bf(b) << 16);
}

// ---- workspace layout (float offsets) ----
constexpr size_t TRI1 = 0;            // B*N*8   tri_1 (masked)
constexpr size_t TRI2 = 4096;
constexpr size_t TRI3 = 8192;
constexpr size_t MSG1 = 12288;        // B*N*128 msg_1 (masked)
constexpr size_t MSG2 = 77824;
constexpr size_t ZWU1 = 143360;
constexpr size_t TRIG = 208896;       // B*8
constexpr size_t MSGG = 209920;       // B*128
constexpr size_t E1T  = 210944;       // B*N*N*8  fp32 [b][j][i][c]
constexpr size_t E2T  = 735232;       // B*N*N*8  fp32 [b][k][i][c]
constexpr size_t E3N  = 1259520;      // B*N*N*8  fp32 [b][j][k][c]
constexpr size_t PREPF = 1783808;     // bf16 prepped weights (ushort region)

// prep (ushort units), MFMA-fragment order:
// ((ks*8 + t)*64 + lane)*8 + jj == W^T[16t + (lane&15)][ks*32 + (lane>>4)*8 + jj]
constexpr int W1T_OFF  = 0;
constexpr int W2T_OFF  = 16384;
constexpr int WMET_OFF = 32768;

// ---- output layout (float offsets): ret, msgs, tri_msgs ----
constexpr size_t O_RET = 0;
constexpr size_t O_MSG = 65536;
constexpr size_t O_TRI = 131072;

__device__ __forceinline__ int detect_int(const void* mask) {
    const unsigned char* m = (const unsigned char*)mask;
    return (m[1] | m[2] | m[3]) == 0 ? 1 : 0;
}
__device__ __forceinline__ bool rdbool(const void* p, size_t idx, int isInt) {
    if (isInt) return ((const int*)p)[idx] != 0;
    return ((const unsigned char*)p)[idx] != 0;
}

// ============================================================
// K1: tri-e projection (0..511, full 128-row blocks) + z proj (512..1023)
//     + graph (1024..1027) + weight prep (1028..1219).  256 thr.
// NOTE: (256,4) NOT (256,8) — the tighter bound caps VGPR at 32 and forces
// scratch spills of bfrag (measured r11: VGPR 32, WRITE_SIZE 2.2x, 2x slower).
// ============================================================
__global__ __launch_bounds__(256, 4) void k_pre(
    const float* __restrict__ z, const float* __restrict__ e, const void* __restrict__ mask,
    const float* __restrict__ Wt1, const float* __restrict__ Wt2, const float* __restrict__ Wt3,
    const float* __restrict__ Wm1, const float* __restrict__ Wm2, const float* __restrict__ WU1,
    const float* __restrict__ g, const float* __restrict__ Wg, const float* __restrict__ Wmg,
    const float* __restrict__ W1, const float* __restrict__ W2, const float* __restrict__ Wme,
    const float* __restrict__ We1, const float* __restrict__ We2, const float* __restrict__ We3,
    float* __restrict__ ws, unsigned short* __restrict__ prep)
{
    int bx = blockIdx.x, tid = threadIdx.x;
    __shared__ __align__(16) unsigned char smem[128 * 136 * 2];

    if (bx < 512) {
        // ---------- tri-e projection: block = one (b,i) ----------
        unsigned short* Ab = (unsigned short*)smem;
        int bi = bx;
        int b = bi >> 7, i = bi & 127;
        int lane = tid & 63, w = tid >> 6, q = lane >> 4, n = lane & 15;
        {
            int half = lane >> 5, c4 = (lane & 31) * 4;
            #pragma unroll
            for (int it = 0; it < 16; it++) {
                int row = 32 * w + 2 * it + half;
                float4 v = *(const float4*)(e + (size_t)bi * 16384 + (size_t)row * 128 + c4);
                unsigned* dst = (unsigned*)&Ab[row * 136 + c4];
                dst[0] = pack2(v.x, v.y);
                dst[1] = pack2(v.z, v.w);
            }
        }
        // gather packed-We B fragments (cols: We1|We2|We3|0), L1-hot 4KB arrays
        short8 bfrag[4][2];
        {
            #pragma unroll
            for (int t = 0; t < 2; t++) {
                int col = 16 * t + n;
                const float* Wsel = (col < 8) ? We1 : (col < 16 ? We2 : We3);
                int csel = col & 7;
                float mval = (col < 24) ? 1.f : 0.f;
                #pragma unroll
                for (int ks = 0; ks < 4; ks++) {
                    union { short8 s; unsigned short u[8]; } tmp;
                    #pragma unroll
                    for (int jj = 0; jj < 8; jj++) {
                        int k = ks * 32 + q * 8 + jj;
                        tmp.u[jj] = f2bf(Wsel[k * 8 + csel] * mval);
                    }
                    bfrag[ks][t] = tmp.s;
                }
            }
        }
        __builtin_amdgcn_wave_barrier();

        f32x4 ac2[2][2];
        #pragma unroll
        for (int rt = 0; rt < 2; rt++)
            #pragma unroll
            for (int t = 0; t < 2; t++) ac2[rt][t] = 0.f;
        #pragma unroll
        for (int ks = 0; ks < 4; ks++) {
            int k0 = ks * 32 + q * 8;
            short8 a0 = *(const short8*)&Ab[(32 * w + n) * 136 + k0];
            short8 a1 = *(const short8*)&Ab[(32 * w + 16 + n) * 136 + k0];
            #pragma unroll
            for (int t = 0; t < 2; t++) {
                ac2[0][t] = MFMA16(a0, bfrag[ks][t], ac2[0][t]);
                ac2[1][t] = MFMA16(a1, bfrag[ks][t], ac2[1][t]);
            }
        }
        #pragma unroll
        for (int rt = 0; rt < 2; rt++)
            #pragma unroll
            for (int reg = 0; reg < 4; reg++) {
                int row = 32 * w + 16 * rt + 4 * q + reg;
                float v0 = ac2[rt][0][reg];
                if (n < 8) ws[E1T + ((size_t)(b * 128 + row) * 128 + i) * 8 + n] = v0;
                else       ws[E2T + ((size_t)(b * 128 + row) * 128 + i) * 8 + (n - 8)] = v0;
                if (n < 8) ws[E3N + ((size_t)bi * 128 + row) * 8 + n] = ac2[rt][1][reg];
            }
        return;
    }
    if (bx < 1024) {
        // ---------- z-row projections (2-way split accumulators for ILP) ----------
        int bn = bx - 512;
        int isInt = detect_int(mask);
        float* zr = (float*)smem;
        zr[tid] = z[(size_t)bn * INF + tid];
        __syncthreads();
        float mk = rdbool(mask, bn, isInt) ? 1.f : 0.f;
        for (int idx = tid; idx < 408; idx += 256) {
            const float* W; int c; size_t dst; int width; bool msk;
            if (idx < 8)        { W = Wt1; c = idx;       dst = TRI1 + (size_t)bn * 8;   width = 8;   msk = true;  }
            else if (idx < 16)  { W = Wt2; c = idx - 8;   dst = TRI2 + (size_t)bn * 8;   width = 8;   msk = true;  }
            else if (idx < 24)  { W = Wt3; c = idx - 16;  dst = TRI3 + (size_t)bn * 8;   width = 8;   msk = true;  }
            else if (idx < 152) { W = Wm1; c = idx - 24;  dst = MSG1 + (size_t)bn * 128; width = 128; msk = true;  }
            else if (idx < 280) { W = Wm2; c = idx - 152; dst = MSG2 + (size_t)bn * 128; width = 128; msk = true;  }
            else                { W = WU1; c = idx - 280; dst = ZWU1 + (size_t)bn * 128; width = 128; msk = false; }
            float a0 = 0.f, a1 = 0.f;
            #pragma unroll 8
            for (int k = 0; k < INF; k += 2) {
                a0 += zr[k] * W[k * width + c];
                a1 += zr[k + 1] * W[(k + 1) * width + c];
            }
            float acc = a0 + a1;
            ws[dst + c] = msk ? acc * mk : acc;
        }
        return;
    }
    if (bx < 1028) {
        // ---------- graph_fts projections ----------
        int b = bx - 1024;
        float* gr = (float*)smem;
        if (tid < 128) gr[tid] = g[b * 128 + tid];
        __syncthreads();
        if (tid < 8) {
            float a = 0.f;
            for (int k = 0; k < 128; k++) a += gr[k] * Wg[k * 8 + tid];
            ws[TRIG + b * 8 + tid] = a;
        } else if (tid >= 128) {
            int c = tid - 128;
            float a = 0.f;
            for (int k = 0; k < 128; k++) a += gr[k] * Wmg[k * 128 + c];
            ws[MSGG + b * 128 + c] = a;
        }
        return;
    }
    // ---------- weight prep (fragment-order), W1/W2/Wme only ----------
    {
        int idx = (bx - 1028) * 256 + tid;   // < 49152
        const float* W = (idx < 16384) ? W1 : (idx < 32768 ? W2 : Wme);
        int local = idx & 16383;
        int f = local >> 3, jj = local & 7;
        int lane = f & 63, fg = f >> 6;
        int t = fg & 7, ks = fg >> 3;
        int n = lane & 15, q = lane >> 4;
        int row = 16 * t + n;
        int k = ks * 32 + q * 8 + jj;
        prep[idx] = f2bf(W[k * 128 + row]);
    }
}

// ============================================================
// K2: pair-MLP blocks (bx%3<2) + triplet-pool blocks (bx%3==2).
// grid 768, block 256, LDS 36.9KB -> 4 blocks/CU.
// Triplet inner loop on ext-vector float4 (packed VALU adds).
// ============================================================
constexpr int PQSTR = 268;   // floats; 268 % 32 = 12

__global__ __launch_bounds__(256, 4) void k_main(
    const float* __restrict__ e, const void* __restrict__ mask, const void* __restrict__ adj,
    const float* __restrict__ ln1s, const float* __restrict__ ln1o,
    const float* __restrict__ ln2s, const float* __restrict__ ln2o,
    const unsigned short* __restrict__ prep, const float* __restrict__ WU3,
    float* __restrict__ ws, float* __restrict__ out)
{
    int bx = blockIdx.x, tid = threadIdx.x;
    int gct = bx / 3, r3 = bx - gct * 3;
    __shared__ __align__(16) unsigned char smem[128 * 136 * 2 + 2048];
    int lane = tid & 63, w = tid >> 6, q = lane >> 4, n = lane & 15;

    if (r3 == 2) {
        // ================= triplet max-plus pooling: 16x16 (j,k) tile =================
        int g = gct;
        int j0 = ((g >> 3) & 7) * 16, k0 = (g & 7) * 16, b = g >> 6;
        int isInt = detect_int(mask);
        float* Pl = (float*)smem;                        // [16][268]
        float* Ql = (float*)(smem + 16 * PQSTR * 4);     // [16][268]
        float* pooled = (float*)smem;                    // alias: [8][260] c-major
        __shared__ unsigned char mloc[128];
        if (tid < 128) mloc[tid] = rdbool(mask, b * 128 + tid, isInt) ? 1 : 0;

        // WU3 fragment in registers (coalesced global loads; L2-hot)
        int col4 = (tid & 31) * 4, rowgrp = tid >> 5;
        float4 wvr[8];
        #pragma unroll
        for (int c = 0; c < 8; c++) wvr[c] = *(const float4*)(WU3 + c * 128 + col4);

        int tj = tid >> 4, tk = tid & 15;
        f32x4 accM[2], accU[2];
        accM[0] = NEGF; accM[1] = NEGF; accU[0] = NEGF; accU[1] = NEGF;

        for (int i0 = 0; i0 < 128; i0 += 32) {
            __syncthreads();   // previous chunk consumed
            {
                float4 t1c = *(const float4*)(ws + TRI1 + (size_t)b * 1024 + i0 * 8 + lane * 4);
                #pragma unroll
                for (int r4 = 0; r4 < 4; r4++) {
                    int row = 4 * w + r4;
                    float4 ev = *(const float4*)(ws + E1T + (size_t)(b * 128 + j0 + row) * 1024 + i0 * 8 + lane * 4);
                    float4 qv = *(const float4*)(ws + E2T + (size_t)(b * 128 + k0 + row) * 1024 + i0 * 8 + lane * 4);
                    float4 pv;
                    pv.x = ev.x + t1c.x; pv.y = ev.y + t1c.y;
                    pv.z = ev.z + t1c.z; pv.w = ev.w + t1c.w;
                    *(float4*)(Pl + row * PQSTR + lane * 4) = pv;   // contiguous 1KB wave write
                    *(float4*)(Ql + row * PQSTR + lane * 4) = qv;
                }
            }
            __syncthreads();   // staged
            const float* pp = Pl + tj * PQSTR;
            const float* qq = Ql + tk * PQSTR;
            for (int ii = 0; ii < 32; ii++) {
                bool m_i = mloc[i0 + ii] != 0;   // wave-uniform
                f32x4 p0 = *(const f32x4*)(pp + ii * 8);
                f32x4 p1 = *(const f32x4*)(pp + ii * 8 + 4);
                f32x4 q0 = *(const f32x4*)(qq + ii * 8);
                f32x4 q1 = *(const f32x4*)(qq + ii * 8 + 4);
                f32x4 v0 = p0 + q0;   // packed fp32 adds
                f32x4 v1 = p1 + q1;
                if (m_i) {
                    accM[0] = __builtin_elementwise_max(accM[0], v0);
                    accM[1] = __builtin_elementwise_max(accM[1], v1);
                } else {
                    accU[0] = __builtin_elementwise_max(accU[0], v0);
                    accU[1] = __builtin_elementwise_max(accU[1], v1);
                }
            }
        }
        f32x4 sel[2];
        {
            bool all_i = (mloc[j0 + tj] | mloc[k0 + tk]) != 0;
            if (all_i) {
                sel[0] = __builtin_elementwise_max(accM[0], accU[0]);
                sel[1] = __builtin_elementwise_max(accM[1], accU[1]);
            } else {
                sel[0] = accM[0]; sel[1] = accM[1];
            }
        }
        __syncthreads();   // P/Q reads done; safe to alias pooled
        {
            const float* t2 = ws + TRI2 + (size_t)(b * 128 + j0 + tj) * 8;
            const float* t3 = ws + TRI3 + (size_t)(b * 128 + k0 + tk) * 8;
            const float* e3 = ws + E3N + ((size_t)(b * 128 + j0 + tj) * 128 + (k0 + tk)) * 8;
            const float* tg = ws + TRIG + (size_t)b * 8;
            #pragma unroll
            for (int c = 0; c < 8; c++)
                pooled[c * 260 + tid] = sel[c >> 2][c & 3] + t2[c] + t3[c] + e3[c] + tg[c];
        }
        __syncthreads();
        // epilogue: relu(pooled @ WU3); pooled reads broadcast, no LDS weights
        #pragma unroll
        for (int pass = 0; pass < 32; pass++) {
            int p = pass * 8 + rowgrp;
            float4 s = { 0.f, 0.f, 0.f, 0.f };
            #pragma unroll
            for (int c = 0; c < 8; c++) {
                float pv = pooled[c * 260 + p];
                s.x += pv * wvr[c].x; s.y += pv * wvr[c].y;
                s.z += pv * wvr[c].z; s.w += pv * wvr[c].w;
            }
            s.x = fmaxf(s.x, 0.f); s.y = fmaxf(s.y, 0.f);
            s.z = fmaxf(s.z, 0.f); s.w = fmaxf(s.w, 0.f);
            int pj = p >> 4, pk = p & 15;
            *(float4*)(out + O_TRI + ((size_t)(b * 128 + j0 + pj) * 128 + (k0 + pk)) * 128 + col4) = s;
        }
        return;
    }

    // ================= pair MLP: block = one (b,j) =================
    unsigned short* Ab = (unsigned short*)smem;
    float* pw = (float*)(smem + 128 * 136 * 2);
    int bj = gct * 2 + r3;
    int b = bj >> 7, j = bj & 127;
    int isInt = detect_int(mask);

    {
        int half = lane >> 5, c4 = (lane & 31) * 4;
        #pragma unroll
        for (int it = 0; it < 16; it++) {
            int row = 32 * w + 2 * it + half;
            float4 v = *(const float4*)(e + (((size_t)b * 128 + row) * 128 + j) * 128 + c4);
            unsigned* dst = (unsigned*)&Ab[row * 136 + c4];
            dst[0] = pack2(v.x, v.y);
            dst[1] = pack2(v.z, v.w);
        }
    }
    __builtin_amdgcn_wave_barrier();

    f32x4 acc[2][8];
    #pragma unroll
    for (int rt = 0; rt < 2; rt++)
        #pragma unroll
        for (int t = 0; t < 8; t++) acc[rt][t] = 0.f;

    #pragma unroll
    for (int ks = 0; ks < 4; ks++) {
        int k0 = ks * 32 + q * 8;
        short8 a0 = *(const short8*)&Ab[(32 * w + n) * 136 + k0];
        short8 a1 = *(const short8*)&Ab[(32 * w + 16 + n) * 136 + k0];
        #pragma unroll
        for (int t = 0; t < 8; t++) {
            short8 bt = *(const short8*)&prep[WMET_OFF + ((ks * 8 + t) * 64 + lane) * 8];
            acc[0][t] = MFMA16(a0, bt, acc[0][t]);
            acc[1][t] = MFMA16(a1, bt, acc[1][t]);
        }
    }

    float msum[8];
    #pragma unroll
    for (int t = 0; t < 8; t++)
        msum[t] = ws[MSG1 + (size_t)bj * 128 + 16 * t + n] + ws[MSGG + (size_t)b * 128 + 16 * t + n];
    float adjm[2][4];
    float rs[2][4], rss[2][4];
    #pragma unroll
    for (int rt = 0; rt < 2; rt++)
        #pragma unroll
        for (int reg = 0; reg < 4; reg++) {
            int row = 32 * w + 16 * rt + 4 * q + reg;
            bool av = rdbool(adj, ((size_t)b * 128 + row) * 128 + j, isInt);
            adjm[rt][reg] = av ? 1.f : 0.f;
            float s = 0.f, ssq = 0.f;
            #pragma unroll
            for (int t = 0; t < 8; t++) {
                float v = acc[rt][t][reg] * adjm[rt][reg]
                        + ws[MSG2 + ((size_t)b * 128 + row) * 128 + 16 * t + n] + msum[t];
                acc[rt][t][reg] = v;
                s += v; ssq += v * v;
            }
            rs[rt][reg] = s; rss[rt][reg] = ssq;
        }
    #pragma unroll
    for (int d = 1; d < 16; d <<= 1) {
        #pragma unroll
        for (int rt = 0; rt < 2; rt++)
            #pragma unroll
            for (int reg = 0; reg < 4; reg++) {
                rs[rt][reg]  += __shfl_xor(rs[rt][reg], d, 64);
                rss[rt][reg] += __shfl_xor(rss[rt][reg], d, 64);
            }
    }
    {
        float s1v[8], o1v[8];
        #pragma unroll
        for (int t = 0; t < 8; t++) { s1v[t] = ln1s[16 * t + n]; o1v[t] = ln1o[16 * t + n]; }
        #pragma unroll
        for (int rt = 0; rt < 2; rt++)
            #pragma unroll
            for (int reg = 0; reg < 4; reg++) {
                float mu = rs[rt][reg] * (1.f / 128);
                float inv = rsqrtf(rss[rt][reg] * (1.f / 128) - mu * mu + EPSF);
                int row = 32 * w + 16 * rt + 4 * q + reg;
                #pragma unroll
                for (int t = 0; t < 8; t++) {
                    float v = fmaxf(s1v[t] * inv * (acc[rt][t][reg] - mu) + o1v[t], 0.f);
                    Ab[row * 136 + 16 * t + n] = f2bf(v);
                }
            }
    }
    __builtin_amdgcn_wave_barrier();

    #pragma unroll
    for (int rt = 0; rt < 2; rt++)
        #pragma unroll
        for (int t = 0; t < 8; t++) acc[rt][t] = 0.f;
    #pragma unroll
    for (int ks = 0; ks < 4; ks++) {
        int k0 = ks * 32 + q * 8;
        short8 a0 = *(const short8*)&Ab[(32 * w + n) * 136 + k0];
        short8 a1 = *(const short8*)&Ab[(32 * w + 16 + n) * 136 + k0];
        #pragma unroll
        for (int t = 0; t < 8; t++) {
            short8 bt = *(const short8*)&prep[W1T_OFF + ((ks * 8 + t) * 64 + lane) * 8];
            acc[0][t] = MFMA16(a0, bt, acc[0][t]);
            acc[1][t] = MFMA16(a1, bt, acc[1][t]);
        }
    }
    #pragma unroll
    for (int rt = 0; rt < 2; rt++)
        #pragma unroll
        for (int reg = 0; reg < 4; reg++) {
            float s = 0.f, ssq = 0.f;
            #pragma unroll
            for (int t = 0; t < 8; t++) { float v = acc[rt][t][reg]; s += v; ssq += v * v; }
            rs[rt][reg] = s; rss[rt][reg] = ssq;
        }
    #pragma unroll
    for (int d = 1; d < 16; d <<= 1) {
        #pragma unroll
        for (int rt = 0; rt < 2; rt++)
            #pragma unroll
            for (int reg = 0; reg < 4; reg++) {
                rs[rt][reg]  += __shfl_xor(rs[rt][reg], d, 64);
                rss[rt][reg] += __shfl_xor(rss[rt][reg], d, 64);
            }
    }
    {
        float s2v[8], o2v[8];
        #pragma unroll
        for (int t = 0; t < 8; t++) { s2v[t] = ln2s[16 * t + n]; o2v[t] = ln2o[16 * t + n]; }
        #pragma unroll
        for (int rt = 0; rt < 2; rt++)
            #pragma unroll
            for (int reg = 0; reg < 4; reg++) {
                float mu = rs[rt][reg] * (1.f / 128);
                float inv = rsqrtf(rss[rt][reg] * (1.f / 128) - mu * mu + EPSF);
                int row = 32 * w + 16 * rt + 4 * q + reg;
                #pragma unroll
                for (int t = 0; t < 8; t++) {
                    float v = fmaxf(s2v[t] * inv * (acc[rt][t][reg] - mu) + o2v[t], 0.f);
                    Ab[row * 136 + 16 * t + n] = f2bf(v);
                }
            }
    }
    __builtin_amdgcn_wave_barrier();

    #pragma unroll
    for (int rt = 0; rt < 2; rt++)
        #pragma unroll
        for (int t = 0; t < 8; t++) acc[rt][t] = 0.f;
    #pragma unroll
    for (int ks = 0; ks < 4; ks++) {
        int k0 = ks * 32 + q * 8;
        short8 a0 = *(const short8*)&Ab[(32 * w + n) * 136 + k0];
        short8 a1 = *(const short8*)&Ab[(32 * w + 16 + n) * 136 + k0];
        #pragma unroll
        for (int t = 0; t < 8; t++) {
            short8 bt = *(const short8*)&prep[W2T_OFF + ((ks * 8 + t) * 64 + lane) * 8];
            acc[0][t] = MFMA16(a0, bt, acc[0][t]);
            acc[1][t] = MFMA16(a1, bt, acc[1][t]);
        }
    }
    float colmax[8];
    #pragma unroll
    for (int t = 0; t < 8; t++) colmax[t] = NEGF;
    #pragma unroll
    for (int rt = 0; rt < 2; rt++)
        #pragma unroll
        for (int reg = 0; reg < 4; reg++) {
            if (adjm[rt][reg] > 0.f) {
                #pragma unroll
                for (int t = 0; t < 8; t++) colmax[t] = fmaxf(colmax[t], acc[rt][t][reg]);
            }
        }
    #pragma unroll
    for (int t = 0; t < 8; t++) {
        colmax[t] = fmaxf(colmax[t], __shfl_xor(colmax[t], 16, 64));
        colmax[t] = fmaxf(colmax[t], __shfl_xor(colmax[t], 32, 64));
    }
    if (lane < 16) {
        #pragma unroll
        for (int t = 0; t < 8; t++) pw[w * 128 + 16 * t + lane] = colmax[t];
    }
    __syncthreads();
    if (tid < 128) {
        float mx = fmaxf(fmaxf(pw[tid], pw[128 + tid]), fmaxf(pw[256 + tid], pw[384 + tid]));
        out[O_MSG + (size_t)bj * 128 + tid] = mx;
    }
}

// ============================================================
// K3: ret = LN(z@WU1 + msgs@WU2).  grid 512, block 128
// ============================================================
__global__ __launch_bounds__(128) void k_final(
    const float* __restrict__ ws, const float* __restrict__ WU2,
    const float* __restrict__ lnfs, const float* __restrict__ lnfo,
    float* __restrict__ out)
{
    int bn = blockIdx.x, tid = threadIdx.x;
    __shared__ float mrow[128];
    __shared__ float red[4];
    mrow[tid] = out[O_MSG + (size_t)bn * 128 + tid];
    __syncthreads();
    float y = ws[ZWU1 + (size_t)bn * 128 + tid];
    #pragma unroll 8
    for (int k = 0; k < 128; k++) y += mrow[k] * WU2[k * 128 + tid];
    float s = y, ss = y * y;
    for (int d = 1; d < 64; d <<= 1) { s += __shfl_xor(s, d, 64); ss += __shfl_xor(ss, d, 64); }
    if ((tid & 63) == 0) { red[(tid >> 6) * 2] = s; red[(tid >> 6) * 2 + 1] = ss; }
    __syncthreads();
    float S = red[0] + red[2], SS = red[1] + red[3];
    float m_ = S * (1.f / 128), v_ = SS * (1.f / 128) - m_ * m_;
    float r = rsqrtf(v_ + EPSF);
    out[O_RET + (size_t)bn * 128 + tid] = lnfs[tid] * r * (y - m_) + lnfo[tid];
}

// ============================================================
extern "C" void kernel_launch(void* const* d_in, const int* in_sizes, int n_in,
                              void* d_out, int out_size, void* d_ws, size_t ws_size,
                              hipStream_t stream)
{
    const float* z    = (const float*)d_in[0];
    const float* e    = (const float*)d_in[1];
    const float* gf   = (const float*)d_in[2];
    const void*  mask = d_in[3];
    const void*  adj  = d_in[4];
    const float* Wt1 = (const float*)d_in[5];
    const float* Wt2 = (const float*)d_in[6];
    const float* Wt3 = (const float*)d_in[7];
    const float* We1 = (const float*)d_in[8];
    const float* We2 = (const float*)d_in[9];
    const float* We3 = (const float*)d_in[10];
    const float* Wg  = (const float*)d_in[11];
    const float* Wm1 = (const float*)d_in[12];
    const float* Wm2 = (const float*)d_in[13];
    const float* Wme = (const float*)d_in[14];
    const float* Wmg = (const float*)d_in[15];
    const float* ln1s = (const float*)d_in[16];
    const float* ln1o = (const float*)d_in[17];
    const float* W1   = (const float*)d_in[18];
    const float* ln2s = (const float*)d_in[19];
    const float* ln2o = (const float*)d_in[20];
    const float* W2   = (const float*)d_in[21];
    const float* WU1  = (const float*)d_in[22];
    const float* WU2  = (const float*)d_in[23];
    const float* WU3  = (const float*)d_in[24];
    const float* lnfs = (const float*)d_in[25];
    const float* lnfo = (const float*)d_in[26];
    float* out = (float*)d_out;
    float* ws  = (float*)d_ws;
    unsigned short* prep = (unsigned short*)(ws + PREPF);

    hipLaunchKernelGGL(k_pre, dim3(1220), dim3(256), 0, stream,
                       z, e, mask, Wt1, Wt2, Wt3, Wm1, Wm2, WU1, gf, Wg, Wmg,
                       W1, W2, Wme, We1, We2, We3, ws, prep);
    hipLaunchKernelGGL(k_main, dim3(768), dim3(256), 0, stream,
                       e, mask, adj, ln1s, ln1o, ln2s, ln2o, prep, WU3, ws, out);
    hipLaunchKernelGGL(k_final, dim3(512), dim3(128), 0, stream,
                       ws, WU2, lnfs, lnfo, out);
}